// Round 6
// baseline (133.275 us; speedup 1.0000x reference)
//
#include <hip/hip_runtime.h>

// DCNv2, fp32 in/out, fully fused MFMA path, barrier-light.
// (1) x NCHW -> xT bf16 NHWC (hi only),
// (2) prep: wd A-frags + wo split (hi/lo) A-frags,
// (3) fused: per-wave 16 px: offset conv (direct B-frag global loads -> MFMA,
//     w split hi+lo) -> offsets to per-wave LDS -> one barrier -> deform
//     (bilinear blend in registers, direct B-frag layout) -> MFMA -> out.
// B-frag layout (verified from passing R5 kernel): n=lane&15, k=(lane>>4)*8+j.
// ws: xT 8388608 B | wdA 73728 B | woAhi 36864 B | woAlo 36864 B

#define BATCH 4
#define CIN   64
#define COUT  64
#define HH    128
#define WW    128
#define HWPIX (HH*WW)

typedef __attribute__((ext_vector_type(8))) short short8;   // 8 bf16 (4 VGPRs)
typedef __attribute__((ext_vector_type(4))) float floatx4;  // MFMA C/D

__device__ __forceinline__ unsigned short f2bf(float f) {   // RNE f32->bf16
  unsigned int u = __float_as_uint(f);
  unsigned int r = u + 0x7fffu + ((u >> 16) & 1u);
  return (unsigned short)(r >> 16);
}
__device__ __forceinline__ float bf2f(unsigned short h) { return __uint_as_float(((unsigned int)h) << 16); }
__device__ __forceinline__ float lo16f(unsigned int u) { return __uint_as_float(u << 16); }
__device__ __forceinline__ float hi16f(unsigned int u) { return __uint_as_float(u & 0xffff0000u); }

__device__ __forceinline__ unsigned int bilin2(unsigned int u00, unsigned int u01,
                                               unsigned int u10, unsigned int u11,
                                               float w00, float w01, float w10, float w11) {
  float lo = w00 * lo16f(u00) + w01 * lo16f(u01) + w10 * lo16f(u10) + w11 * lo16f(u11);
  float hi = w00 * hi16f(u00) + w01 * hi16f(u01) + w10 * hi16f(u10) + w11 * hi16f(u11);
  return (unsigned int)f2bf(lo) | ((unsigned int)f2bf(hi) << 16);
}

// x fp32 NCHW -> xT bf16 [b][px][cin]
__global__ __launch_bounds__(256) void transpose_x_kernel(const float* __restrict__ x,
                                                          unsigned short* __restrict__ xT) {
  __shared__ float tile[32][33];   // [c_local][p_local]
  int b = blockIdx.z, p0 = blockIdx.x * 32, c0 = blockIdx.y * 32;
  int tx = threadIdx.x, ty = threadIdx.y;        // (32,8)
  const float* xb = x + (size_t)b * CIN * HWPIX;
  unsigned short* xTb = xT + (size_t)b * HWPIX * CIN;
#pragma unroll
  for (int i = 0; i < 4; i++)
    tile[ty + i * 8][tx] = xb[(size_t)(c0 + ty + i * 8) * HWPIX + p0 + tx];
  __syncthreads();
  int wid = ty * 32 + tx;
#pragma unroll
  for (int i = 0; i < 2; i++) {
    int t = wid + i * 256;        // 0..511 = 32 rows * 16 cin-pairs
    int row = t >> 4;
    int cp = t & 15;
    ushort2 v = make_ushort2(f2bf(tile[cp * 2][row]), f2bf(tile[cp * 2 + 1][row]));
    *(ushort2*)&xTb[(size_t)(p0 + row) * CIN + c0 + cp * 2] = v;
  }
}

// wdA[kk][kc2][ct4][lane][j] bf16 (36864 entries);
// woAhi/lo[kk][kc2][ct2][lane][j] bf16 (M=32 rows, rows>=18 zero; 18432 each)
__global__ __launch_bounds__(256) void prep_weights_kernel(const float* __restrict__ wo,
                                                           const float* __restrict__ wd,
                                                           unsigned short* __restrict__ wdA,
                                                           unsigned short* __restrict__ woAhi,
                                                           unsigned short* __restrict__ woAlo) {
  int t = blockIdx.x * 256 + threadIdx.x;
  if (t < 36864) {
    int j = t & 7, lane = (t >> 3) & 63, ct = (t >> 9) & 3, kc = (t >> 11) & 1, kk = t >> 12;
    int cout = ct * 16 + (lane & 15);
    int cin  = kc * 32 + (lane >> 4) * 8 + j;
    wdA[t] = f2bf(wd[(size_t)(cout * CIN + cin) * 9 + kk]);
  }
  int t2 = t - 36864;
  if (t2 >= 0 && t2 < 18432) {
    int j = t2 & 7, lane = (t2 >> 3) & 63, ct = (t2 >> 9) & 1, kc = (t2 >> 10) & 1, kk = t2 >> 11;
    int cout = ct * 16 + (lane & 15);          // conv channel 0..31 (valid < 18)
    int cin  = kc * 32 + (lane >> 4) * 8 + j;
    float v = (cout < 18) ? wo[(size_t)(cout * CIN + cin) * 9 + kk] : 0.f;
    unsigned short h = f2bf(v);
    woAhi[t2] = h;
    woAlo[t2] = f2bf(v - bf2f(h));
  }
}

// Fused offset-conv + deform. Block = 4 waves; each wave owns 16 px of one row.
__global__ __launch_bounds__(256) void fused_dcn_kernel(const unsigned short* __restrict__ xT,
                                                        const unsigned short* __restrict__ wdA,
                                                        const unsigned short* __restrict__ woAhi,
                                                        const unsigned short* __restrict__ woAlo,
                                                        float* __restrict__ out) {
  __shared__ float offsL[4][18][16];   // [wave][conv-ch][px] 4.5 KB
  int tid = threadIdx.x;
  int lane = tid & 63, w = tid >> 6;
  int hw = blockIdx.x;
  int bid = (hw & 7) * 128 + (hw >> 3);  // XCD-contiguous y bands
  int b = bid >> 8, r = bid & 255, y = r >> 1, x0 = (r & 1) << 6;

  int pxl = lane & 15;                  // px within wave tile (B-frag n)
  int px  = x0 + w * 16 + pxl;          // x coordinate
  int klo = (lane >> 4) * 8;            // cin sub-offset within kc chunk (B-frag k)
  int rowb = (lane >> 4) * 4;           // D-frag row base

  const unsigned short* xTb = xT + (size_t)b * HWPIX * CIN;

  // ---------- phase A: offset conv (M=32 pad, split-bf16 weights) ----------
  {
    floatx4 oacc[2];
    oacc[0] = (floatx4){0.f, 0.f, 0.f, 0.f};
    oacc[1] = (floatx4){0.f, 0.f, 0.f, 0.f};
    const short8 zero8 = {0, 0, 0, 0, 0, 0, 0, 0};
#pragma unroll 1
    for (int kk = 0; kk < 9; kk++) {
      int ys = y - 1 + kk / 3;
      int xs = px - 1 + kk % 3;
      bool valid = (ys >= 0) && (ys < HH) && (xs >= 0) && (xs < WW);
      short8 b0 = zero8, b1 = zero8;
      if (valid) {
        const unsigned short* p = xTb + (size_t)(ys * WW + xs) * CIN + klo;
        b0 = *(const short8*)p;
        b1 = *(const short8*)(p + 32);
      }
      const short8* Ah = (const short8*)(woAhi + (size_t)kk * 2048);
      const short8* Al = (const short8*)(woAlo + (size_t)kk * 2048);
#pragma unroll
      for (int ct = 0; ct < 2; ct++) {
        short8 ah0 = Ah[ct * 64 + lane],       al0 = Al[ct * 64 + lane];
        short8 ah1 = Ah[128 + ct * 64 + lane], al1 = Al[128 + ct * 64 + lane];
        oacc[ct] = __builtin_amdgcn_mfma_f32_16x16x32_bf16(ah0, b0, oacc[ct], 0, 0, 0);
        oacc[ct] = __builtin_amdgcn_mfma_f32_16x16x32_bf16(al0, b0, oacc[ct], 0, 0, 0);
        oacc[ct] = __builtin_amdgcn_mfma_f32_16x16x32_bf16(ah1, b1, oacc[ct], 0, 0, 0);
        oacc[ct] = __builtin_amdgcn_mfma_f32_16x16x32_bf16(al1, b1, oacc[ct], 0, 0, 0);
      }
    }
#pragma unroll
    for (int ct = 0; ct < 2; ct++)
#pragma unroll
      for (int rr = 0; rr < 4; rr++) {
        int row = ct * 16 + rowb + rr;
        if (row < 18) offsL[w][row][pxl] = oacc[ct][rr];
      }
  }
  __syncthreads();

  // ---------- phase B: deform sample + contraction ----------
  floatx4 acc[4];
#pragma unroll
  for (int ct = 0; ct < 4; ct++) acc[ct] = (floatx4){0.f, 0.f, 0.f, 0.f};

#pragma unroll 1
  for (int kk = 0; kk < 9; kk++) {
    float dy = offsL[w][2 * kk][pxl];
    float dx = offsL[w][2 * kk + 1][pxl];
    float ysf = (float)(y - 1 + kk / 3) + dy;
    float xsf = (float)(px - 1 + kk % 3) + dx;
    float y0f = floorf(ysf), x0f = floorf(xsf);
    float wy = ysf - y0f, wx = xsf - x0f;
    int iy0 = (int)y0f, ix0 = (int)x0f;
    int iy1 = iy0 + 1, ix1 = ix0 + 1;
    float w00 = (1.f - wy) * (1.f - wx), w01 = (1.f - wy) * wx;
    float w10 = wy * (1.f - wx), w11 = wy * wx;
    bool vy0 = (iy0 >= 0) && (iy0 < HH), vy1 = (iy1 >= 0) && (iy1 < HH);
    bool vx0 = (ix0 >= 0) && (ix0 < WW), vx1 = (ix1 >= 0) && (ix1 < WW);
    if (!(vy0 && vx0)) w00 = 0.f;
    if (!(vy0 && vx1)) w01 = 0.f;
    if (!(vy1 && vx0)) w10 = 0.f;
    if (!(vy1 && vx1)) w11 = 0.f;
    int cy0 = min(max(iy0, 0), HH - 1), cy1 = min(max(iy1, 0), HH - 1);
    int cx0 = min(max(ix0, 0), WW - 1), cx1 = min(max(ix1, 0), WW - 1);
    const unsigned short* q00 = xTb + (size_t)(cy0 * WW + cx0) * CIN + klo;
    const unsigned short* q01 = xTb + (size_t)(cy0 * WW + cx1) * CIN + klo;
    const unsigned short* q10 = xTb + (size_t)(cy1 * WW + cx0) * CIN + klo;
    const unsigned short* q11 = xTb + (size_t)(cy1 * WW + cx1) * CIN + klo;
    uint4 c00a = *(const uint4*)q00,        c01a = *(const uint4*)q01;
    uint4 c10a = *(const uint4*)q10,        c11a = *(const uint4*)q11;
    uint4 c00b = *(const uint4*)(q00 + 32), c01b = *(const uint4*)(q01 + 32);
    uint4 c10b = *(const uint4*)(q10 + 32), c11b = *(const uint4*)(q11 + 32);
    uint4 u0, u1;
    u0.x = bilin2(c00a.x, c01a.x, c10a.x, c11a.x, w00, w01, w10, w11);
    u0.y = bilin2(c00a.y, c01a.y, c10a.y, c11a.y, w00, w01, w10, w11);
    u0.z = bilin2(c00a.z, c01a.z, c10a.z, c11a.z, w00, w01, w10, w11);
    u0.w = bilin2(c00a.w, c01a.w, c10a.w, c11a.w, w00, w01, w10, w11);
    u1.x = bilin2(c00b.x, c01b.x, c10b.x, c11b.x, w00, w01, w10, w11);
    u1.y = bilin2(c00b.y, c01b.y, c10b.y, c11b.y, w00, w01, w10, w11);
    u1.z = bilin2(c00b.z, c01b.z, c10b.z, c11b.z, w00, w01, w10, w11);
    u1.w = bilin2(c00b.w, c01b.w, c10b.w, c11b.w, w00, w01, w10, w11);
    short8 bv0 = *(short8*)&u0, bv1 = *(short8*)&u1;
    const short8* Ap = (const short8*)(wdA + (size_t)kk * 4096);
#pragma unroll
    for (int ct = 0; ct < 4; ct++) {
      acc[ct] = __builtin_amdgcn_mfma_f32_16x16x32_bf16(Ap[ct * 64 + lane], bv0, acc[ct], 0, 0, 0);
      acc[ct] = __builtin_amdgcn_mfma_f32_16x16x32_bf16(Ap[256 + ct * 64 + lane], bv1, acc[ct], 0, 0, 0);
    }
  }

  // D: col = lane&15 (px), row = rowb + reg (cout within ct tile)
  float* outb = out + (size_t)b * COUT * HWPIX + y * WW + px;
#pragma unroll
  for (int ct = 0; ct < 4; ct++)
#pragma unroll
    for (int rr = 0; rr < 4; rr++)
      outb[(size_t)(ct * 16 + rowb + rr) * HWPIX] = acc[ct][rr];
}

extern "C" void kernel_launch(void* const* d_in, const int* in_sizes, int n_in,
                              void* d_out, int out_size, void* d_ws, size_t ws_size,
                              hipStream_t stream) {
  const float* x  = (const float*)d_in[0];
  const float* wo = (const float*)d_in[1];
  const float* wd = (const float*)d_in[2];
  float* out = (float*)d_out;

  char* wsb = (char*)d_ws;
  unsigned short* xT    = (unsigned short*)wsb;                      // 8,388,608 B
  unsigned short* wdA   = (unsigned short*)(wsb + 8388608);          // 73,728 B
  unsigned short* woAhi = (unsigned short*)(wsb + 8388608 + 73728);  // 36,864 B
  unsigned short* woAlo = (unsigned short*)(wsb + 8388608 + 110592); // 36,864 B

  transpose_x_kernel<<<dim3(HWPIX / 32, CIN / 32, BATCH), dim3(32, 8, 1), 0, stream>>>(x, xT);
  prep_weights_kernel<<<dim3(216), dim3(256), 0, stream>>>(wo, wd, wdA, woAhi, woAlo);
  fused_dcn_kernel<<<dim3(BATCH * HWPIX / 64), dim3(256), 0, stream>>>(xT, wdA, woAhi, woAlo, out);
}

// Round 7
// 132.039 us; speedup vs baseline: 1.0094x; 1.0094x over previous
//
#include <hip/hip_runtime.h>

// DCNv2, fp32 in/out, fused MFMA path with 2-stage software pipeline.
// (1) x NCHW -> xT bf16 NHWC,
// (2) prep: wd A-frags + wo split (hi/lo) A-frags,
// (3) fused: per-wave 16 px: offset conv (pipelined direct B-frag loads -> MFMA)
//     -> offsets to per-wave LDS -> one barrier -> deform (pipelined gathers,
//     register bilinear blend) -> MFMA -> out.
// B-frag layout: n=lane&15, k=(lane>>4)*8+j.  D: col=lane&15, row=(lane>>4)*4+reg.
// ws: xT 8388608 B | wdA 73728 B | woAhi 36864 B | woAlo 36864 B

#define BATCH 4
#define CIN   64
#define COUT  64
#define HH    128
#define WW    128
#define HWPIX (HH*WW)

typedef __attribute__((ext_vector_type(8))) short short8;   // 8 bf16 (4 VGPRs)
typedef __attribute__((ext_vector_type(4))) float floatx4;  // MFMA C/D

__device__ __forceinline__ unsigned short f2bf(float f) {   // RNE f32->bf16
  unsigned int u = __float_as_uint(f);
  unsigned int r = u + 0x7fffu + ((u >> 16) & 1u);
  return (unsigned short)(r >> 16);
}
__device__ __forceinline__ float bf2f(unsigned short h) { return __uint_as_float(((unsigned int)h) << 16); }
__device__ __forceinline__ float lo16f(unsigned int u) { return __uint_as_float(u << 16); }
__device__ __forceinline__ float hi16f(unsigned int u) { return __uint_as_float(u & 0xffff0000u); }

__device__ __forceinline__ unsigned int bilin2(unsigned int u00, unsigned int u01,
                                               unsigned int u10, unsigned int u11,
                                               float w00, float w01, float w10, float w11) {
  float lo = w00 * lo16f(u00) + w01 * lo16f(u01) + w10 * lo16f(u10) + w11 * lo16f(u11);
  float hi = w00 * hi16f(u00) + w01 * hi16f(u01) + w10 * hi16f(u10) + w11 * hi16f(u11);
  return (unsigned int)f2bf(lo) | ((unsigned int)f2bf(hi) << 16);
}

// x fp32 NCHW -> xT bf16 [b][px][cin]
__global__ __launch_bounds__(256) void transpose_x_kernel(const float* __restrict__ x,
                                                          unsigned short* __restrict__ xT) {
  __shared__ float tile[32][33];   // [c_local][p_local]
  int b = blockIdx.z, p0 = blockIdx.x * 32, c0 = blockIdx.y * 32;
  int tx = threadIdx.x, ty = threadIdx.y;        // (32,8)
  const float* xb = x + (size_t)b * CIN * HWPIX;
  unsigned short* xTb = xT + (size_t)b * HWPIX * CIN;
#pragma unroll
  for (int i = 0; i < 4; i++)
    tile[ty + i * 8][tx] = xb[(size_t)(c0 + ty + i * 8) * HWPIX + p0 + tx];
  __syncthreads();
  int wid = ty * 32 + tx;
#pragma unroll
  for (int i = 0; i < 2; i++) {
    int t = wid + i * 256;        // 0..511 = 32 rows * 16 cin-pairs
    int row = t >> 4;
    int cp = t & 15;
    ushort2 v = make_ushort2(f2bf(tile[cp * 2][row]), f2bf(tile[cp * 2 + 1][row]));
    *(ushort2*)&xTb[(size_t)(p0 + row) * CIN + c0 + cp * 2] = v;
  }
}

// wdA[kk][kc2][ct4][lane][j] bf16 (36864 entries);
// woAhi/lo[kk][kc2][ct2][lane][j] bf16 (M=32 rows, rows>=18 zero; 18432 each)
__global__ __launch_bounds__(256) void prep_weights_kernel(const float* __restrict__ wo,
                                                           const float* __restrict__ wd,
                                                           unsigned short* __restrict__ wdA,
                                                           unsigned short* __restrict__ woAhi,
                                                           unsigned short* __restrict__ woAlo) {
  int t = blockIdx.x * 256 + threadIdx.x;
  if (t < 36864) {
    int j = t & 7, lane = (t >> 3) & 63, ct = (t >> 9) & 3, kc = (t >> 11) & 1, kk = t >> 12;
    int cout = ct * 16 + (lane & 15);
    int cin  = kc * 32 + (lane >> 4) * 8 + j;
    wdA[t] = f2bf(wd[(size_t)(cout * CIN + cin) * 9 + kk]);
  }
  int t2 = t - 36864;
  if (t2 >= 0 && t2 < 18432) {
    int j = t2 & 7, lane = (t2 >> 3) & 63, ct = (t2 >> 9) & 1, kc = (t2 >> 10) & 1, kk = t2 >> 11;
    int cout = ct * 16 + (lane & 15);          // conv channel 0..31 (valid < 18)
    int cin  = kc * 32 + (lane >> 4) * 8 + j;
    float v = (cout < 18) ? wo[(size_t)(cout * CIN + cin) * 9 + kk] : 0.f;
    unsigned short h = f2bf(v);
    woAhi[t2] = h;
    woAlo[t2] = f2bf(v - bf2f(h));
  }
}

// Fused offset-conv + deform, 2-stage pipelined. Block = 4 waves x 16 px.
__global__ __launch_bounds__(256) void fused_dcn_kernel(const unsigned short* __restrict__ xT,
                                                        const unsigned short* __restrict__ wdA,
                                                        const unsigned short* __restrict__ woAhi,
                                                        const unsigned short* __restrict__ woAlo,
                                                        float* __restrict__ out) {
  __shared__ float offsL[4][18][16];   // [wave][conv-ch][px] 4.5 KB
  int tid = threadIdx.x;
  int lane = tid & 63, w = tid >> 6;
  int hw = blockIdx.x;
  int bid = (hw & 7) * 128 + (hw >> 3);  // XCD-contiguous y bands
  int b = bid >> 8, r = bid & 255, y = r >> 1, x0 = (r & 1) << 6;

  int pxl = lane & 15;                  // px within wave tile (B-frag n)
  int px  = x0 + w * 16 + pxl;          // x coordinate
  int klo = (lane >> 4) * 8;            // cin sub-offset (B-frag k)
  int rowb = (lane >> 4) * 4;           // D-frag row base

  const unsigned short* xTb = xT + (size_t)b * HWPIX * CIN;
  const short8 zero8 = {0, 0, 0, 0, 0, 0, 0, 0};

  // ---------- phase A: offset conv, pipelined ----------
  {
    floatx4 oacc[2];
    oacc[0] = (floatx4){0.f, 0.f, 0.f, 0.f};
    oacc[1] = (floatx4){0.f, 0.f, 0.f, 0.f};

    auto loadA = [&](int kk, short8& b0v, short8& b1v) {
      int ys = y - 1 + kk / 3;
      int xs = px - 1 + kk % 3;
      b0v = zero8; b1v = zero8;
      if (ys >= 0 && ys < HH && xs >= 0 && xs < WW) {
        const unsigned short* p = xTb + (size_t)(ys * WW + xs) * CIN + klo;
        b0v = *(const short8*)p;
        b1v = *(const short8*)(p + 32);
      }
    };

    short8 cb0 = zero8, cb1 = zero8;
    loadA(0, cb0, cb1);
#pragma unroll
    for (int kk = 0; kk < 9; kk++) {
      short8 nb0 = zero8, nb1 = zero8;
      if (kk < 8) loadA(kk + 1, nb0, nb1);     // next-stage loads in flight
      const short8* Ah = (const short8*)(woAhi + (size_t)kk * 2048);
      const short8* Al = (const short8*)(woAlo + (size_t)kk * 2048);
#pragma unroll
      for (int ct = 0; ct < 2; ct++) {
        oacc[ct] = __builtin_amdgcn_mfma_f32_16x16x32_bf16(Ah[ct * 64 + lane],       cb0, oacc[ct], 0, 0, 0);
        oacc[ct] = __builtin_amdgcn_mfma_f32_16x16x32_bf16(Al[ct * 64 + lane],       cb0, oacc[ct], 0, 0, 0);
        oacc[ct] = __builtin_amdgcn_mfma_f32_16x16x32_bf16(Ah[128 + ct * 64 + lane], cb1, oacc[ct], 0, 0, 0);
        oacc[ct] = __builtin_amdgcn_mfma_f32_16x16x32_bf16(Al[128 + ct * 64 + lane], cb1, oacc[ct], 0, 0, 0);
      }
      cb0 = nb0; cb1 = nb1;
    }
#pragma unroll
    for (int ct = 0; ct < 2; ct++)
#pragma unroll
      for (int rr = 0; rr < 4; rr++) {
        int row = ct * 16 + rowb + rr;
        if (row < 18) offsL[w][row][pxl] = oacc[ct][rr];
      }
  }
  __syncthreads();

  // ---------- phase B: deform sample + contraction, pipelined ----------
  floatx4 acc[4];
#pragma unroll
  for (int ct = 0; ct < 4; ct++) acc[ct] = (floatx4){0.f, 0.f, 0.f, 0.f};

  // corner order: [c00a,c00b,c01a,c01b,c10a,c10b,c11a,c11b]
  auto loadB = [&](int kk, uint4 (&c)[8], float4& wt) {
    float dy = offsL[w][2 * kk][pxl];
    float dx = offsL[w][2 * kk + 1][pxl];
    float ysf = (float)(y - 1 + kk / 3) + dy;
    float xsf = (float)(px - 1 + kk % 3) + dx;
    float y0f = floorf(ysf), x0f = floorf(xsf);
    float wy = ysf - y0f, wx = xsf - x0f;
    int iy0 = (int)y0f, ix0 = (int)x0f;
    int iy1 = iy0 + 1, ix1 = ix0 + 1;
    float w00 = (1.f - wy) * (1.f - wx), w01 = (1.f - wy) * wx;
    float w10 = wy * (1.f - wx), w11 = wy * wx;
    bool vy0 = (iy0 >= 0) && (iy0 < HH), vy1 = (iy1 >= 0) && (iy1 < HH);
    bool vx0 = (ix0 >= 0) && (ix0 < WW), vx1 = (ix1 >= 0) && (ix1 < WW);
    if (!(vy0 && vx0)) w00 = 0.f;
    if (!(vy0 && vx1)) w01 = 0.f;
    if (!(vy1 && vx0)) w10 = 0.f;
    if (!(vy1 && vx1)) w11 = 0.f;
    wt = make_float4(w00, w01, w10, w11);
    int cy0 = min(max(iy0, 0), HH - 1), cy1 = min(max(iy1, 0), HH - 1);
    int cx0 = min(max(ix0, 0), WW - 1), cx1 = min(max(ix1, 0), WW - 1);
    const unsigned short* q00 = xTb + (size_t)(cy0 * WW + cx0) * CIN + klo;
    const unsigned short* q01 = xTb + (size_t)(cy0 * WW + cx1) * CIN + klo;
    const unsigned short* q10 = xTb + (size_t)(cy1 * WW + cx0) * CIN + klo;
    const unsigned short* q11 = xTb + (size_t)(cy1 * WW + cx1) * CIN + klo;
    c[0] = *(const uint4*)q00; c[1] = *(const uint4*)(q00 + 32);
    c[2] = *(const uint4*)q01; c[3] = *(const uint4*)(q01 + 32);
    c[4] = *(const uint4*)q10; c[5] = *(const uint4*)(q10 + 32);
    c[6] = *(const uint4*)q11; c[7] = *(const uint4*)(q11 + 32);
  };

  uint4 cc[8]; float4 cw;
  loadB(0, cc, cw);
#pragma unroll
  for (int kk = 0; kk < 9; kk++) {
    uint4 nc[8] = {}; float4 nw = make_float4(0.f, 0.f, 0.f, 0.f);
    if (kk < 8) loadB(kk + 1, nc, nw);       // next-stage gathers in flight
    uint4 u0, u1;
    u0.x = bilin2(cc[0].x, cc[2].x, cc[4].x, cc[6].x, cw.x, cw.y, cw.z, cw.w);
    u0.y = bilin2(cc[0].y, cc[2].y, cc[4].y, cc[6].y, cw.x, cw.y, cw.z, cw.w);
    u0.z = bilin2(cc[0].z, cc[2].z, cc[4].z, cc[6].z, cw.x, cw.y, cw.z, cw.w);
    u0.w = bilin2(cc[0].w, cc[2].w, cc[4].w, cc[6].w, cw.x, cw.y, cw.z, cw.w);
    u1.x = bilin2(cc[1].x, cc[3].x, cc[5].x, cc[7].x, cw.x, cw.y, cw.z, cw.w);
    u1.y = bilin2(cc[1].y, cc[3].y, cc[5].y, cc[7].y, cw.x, cw.y, cw.z, cw.w);
    u1.z = bilin2(cc[1].z, cc[3].z, cc[5].z, cc[7].z, cw.x, cw.y, cw.z, cw.w);
    u1.w = bilin2(cc[1].w, cc[3].w, cc[5].w, cc[7].w, cw.x, cw.y, cw.z, cw.w);
    short8 bv0 = *(short8*)&u0, bv1 = *(short8*)&u1;
    const short8* Ap = (const short8*)(wdA + (size_t)kk * 4096);
#pragma unroll
    for (int ct = 0; ct < 4; ct++) {
      acc[ct] = __builtin_amdgcn_mfma_f32_16x16x32_bf16(Ap[ct * 64 + lane],       bv0, acc[ct], 0, 0, 0);
      acc[ct] = __builtin_amdgcn_mfma_f32_16x16x32_bf16(Ap[256 + ct * 64 + lane], bv1, acc[ct], 0, 0, 0);
    }
#pragma unroll
    for (int i = 0; i < 8; i++) cc[i] = nc[i];
    cw = nw;
  }

  // D: col = lane&15 (px), row = rowb + reg (cout within ct tile)
  float* outb = out + (size_t)b * COUT * HWPIX + y * WW + px;
#pragma unroll
  for (int ct = 0; ct < 4; ct++)
#pragma unroll
    for (int rr = 0; rr < 4; rr++)
      outb[(size_t)(ct * 16 + rowb + rr) * HWPIX] = acc[ct][rr];
}

extern "C" void kernel_launch(void* const* d_in, const int* in_sizes, int n_in,
                              void* d_out, int out_size, void* d_ws, size_t ws_size,
                              hipStream_t stream) {
  const float* x  = (const float*)d_in[0];
  const float* wo = (const float*)d_in[1];
  const float* wd = (const float*)d_in[2];
  float* out = (float*)d_out;

  char* wsb = (char*)d_ws;
  unsigned short* xT    = (unsigned short*)wsb;                      // 8,388,608 B
  unsigned short* wdA   = (unsigned short*)(wsb + 8388608);          // 73,728 B
  unsigned short* woAhi = (unsigned short*)(wsb + 8388608 + 73728);  // 36,864 B
  unsigned short* woAlo = (unsigned short*)(wsb + 8388608 + 110592); // 36,864 B

  transpose_x_kernel<<<dim3(HWPIX / 32, CIN / 32, BATCH), dim3(32, 8, 1), 0, stream>>>(x, xT);
  prep_weights_kernel<<<dim3(216), dim3(256), 0, stream>>>(wo, wd, wdA, woAhi, woAlo);
  fused_dcn_kernel<<<dim3(BATCH * HWPIX / 64), dim3(256), 0, stream>>>(xT, wdA, woAhi, woAlo, out);
}